// Round 2
// baseline (114.064 us; speedup 1.0000x reference)
//
#include <hip/hip_runtime.h>
#include <math.h>

#define G      26
#define NA     5
#define NC     20
#define NB     128
#define NT     1024
#define GG     (G*G)            // 676
#define CELLS  (NB*NA*GG)       // 432640
#define CH     (NC+5)           // 25
#define IGNORE_THRESH 0.6f
#define OBJ_SCALE   5.0f
#define NOOBJ_SCALE 1.0f
#define CLS_SCALE   1.0f
#define COORD_SCALE 1.0f
#define STRIDE_F    32.0f

__device__ __constant__ float c_aw[NA] = {1.08f, 3.42f, 6.63f, 9.42f, 16.62f};
__device__ __constant__ float c_ah[NA] = {1.19f, 4.41f, 11.38f, 5.11f, 10.52f};

__device__ __forceinline__ float sigmoidf(float v) {
    return 1.0f / (1.0f + expf(-v));
}

// -------- Pass 1: per-target analysis, dedup, correction lists --------
// One block of 1024 threads. Replaces all memsets + scatter arrays.
__launch_bounds__(1024)
__global__ void k_prep(const float* __restrict__ tg,
                       float* __restrict__ acc,
                       int* __restrict__ counts,
                       int2* __restrict__ obj_list,
                       int* __restrict__ supp_list) {
    __shared__ int packed[NT];
    __shared__ int s_nobj, s_nsupp;
    int t = threadIdx.x;
    if (t == 0) { s_nobj = 0; s_nsupp = 0; }
    if (t < 16) acc[t] = 0.0f;

    int   b  = (int)tg[t * 6 + 0];
    float cx = tg[t * 6 + 2] * (float)G;
    float cy = tg[t * 6 + 3] * (float)G;
    float gw = tg[t * 6 + 4] * (float)G;
    float gh = tg[t * 6 + 5] * (float)G;
    int gi = (int)floorf(cx);
    int gj = (int)floorf(cy);

    float best = -1.0f;
    int bn = 0, bits = 0;
    #pragma unroll
    for (int a = 0; a < NA; ++a) {
        float inter = fminf(c_aw[a], gw) * fminf(c_ah[a], gh);
        float uni   = c_aw[a] * c_ah[a] + 1e-16f + gw * gh - inter;
        float iou   = inter / uni;
        if (iou > best) { best = iou; bn = a; }      // first max wins (jnp.argmax)
        if (iou > IGNORE_THRESH) bits |= (1 << a);
    }
    int key = (b * G + gj) * G + gi;                 // < 86528, fits 17 bits
    packed[t] = (key << 8) | (bn << 5) | bits;
    __syncthreads();

    // unified O(NT) scan over shared: winner (last-wins), obj-anchor set,
    // earlier-suppression dedup
    int me = packed[t];
    int mykey = me >> 8, mybn = (me >> 5) & 7;
    bool winner = true;
    int used = 0, earlier = 0;
    for (int o = 0; o < NT; ++o) {
        int pv = packed[o];
        if ((pv >> 8) != mykey) continue;
        int obn = (pv >> 5) & 7;
        used |= (1 << obn);
        if (o > t && obn == mybn) winner = false;    // a later target owns this cell
        if (o < t) earlier |= (pv & 31);             // earlier rep for suppression
    }

    int cell0 = b * (NA * GG) + gj * G + gi;
    if (winner) {
        int idx = atomicAdd(&s_nobj, 1);
        obj_list[idx] = make_int2(cell0 + mybn * GG, t);
    }
    #pragma unroll
    for (int a = 0; a < NA; ++a) {
        if ((bits >> a & 1) && !(earlier >> a & 1) && !(used >> a & 1)) {
            int idx = atomicAdd(&s_nsupp, 1);
            supp_list[idx] = cell0 + a * GG;         // suppressed, not an obj cell
        }
    }
    __syncthreads();
    if (t == 0) { counts[0] = s_nobj; counts[1] = s_nsupp; }
}

// -------- Pass 2: pure streaming elementwise + default noobj sum --------
__launch_bounds__(256)
__global__ void k_main(const float* __restrict__ x,
                       float* __restrict__ out,
                       float* __restrict__ acc) {
    __shared__ float stage[256 * CH];   // 25600 B
    __shared__ float red[4];

    int cell = blockIdx.x * 256 + threadIdx.x;
    int i = cell % G;
    int j = (cell / G) % G;
    int a = (cell / GG) % NA;
    int b = cell / (NA * GG);

    const float* xp = x + ((size_t)(b * (NA * CH) + a * CH) * GG + (size_t)(j * G + i));
    float v[CH];
    #pragma unroll
    for (int c = 0; c < CH; ++c) v[c] = xp[(size_t)c * GG];

    float px = sigmoidf(v[0]);
    float py = sigmoidf(v[1]);
    float pconf = sigmoidf(v[4]);
    float bx = px + (float)i;
    float by = py + (float)j;
    float bw = expf(v[2]) * c_aw[a];
    float bh = expf(v[3]) * c_ah[a];

    float* s = &stage[threadIdx.x * CH];
    s[0] = bx * STRIDE_F;
    s[1] = by * STRIDE_F;
    s[2] = bw * STRIDE_F;
    s[3] = bh * STRIDE_F;
    s[4] = pconf;
    #pragma unroll
    for (int c = 0; c < NC; ++c) s[5 + c] = sigmoidf(v[5 + c]);

    // default: every cell is a noobj cell -> sum pconf^2 (count handled in k_final)
    float p = pconf * pconf;
    #pragma unroll
    for (int o = 32; o > 0; o >>= 1) p += __shfl_down(p, o);
    if ((threadIdx.x & 63) == 0) red[threadIdx.x >> 6] = p;
    __syncthreads();
    if (threadIdx.x == 0)
        atomicAdd(&acc[5], red[0] + red[1] + red[2] + red[3]);

    // coalesced copy-out: block covers 256*25 contiguous floats
    float* ob = out + (size_t)blockIdx.x * (256 * CH);
    #pragma unroll
    for (int k = 0; k < CH; ++k)
        ob[k * 256 + threadIdx.x] = stage[k * 256 + threadIdx.x];
}

// -------- Pass 3: sparse corrections (obj cells + suppressed cells) --------
__launch_bounds__(256)
__global__ void k_corr(const float* __restrict__ x,
                       const float* __restrict__ tg,
                       const int* __restrict__ counts,
                       const int2* __restrict__ obj_list,
                       const int* __restrict__ supp_list,
                       float* __restrict__ acc) {
    __shared__ float red[4][9];
    int gid = blockIdx.x * 256 + threadIdx.x;

    float p[9];
    #pragma unroll
    for (int q = 0; q < 9; ++q) p[q] = 0.0f;

    if (gid < NT) {
        if (gid < counts[0]) {                       // obj item
            int2 it = obj_list[gid];
            int cell = it.x, t = it.y;
            int b = cell / (NA * GG);
            int a = (cell / GG) % NA;
            int sp = cell % GG;
            int i = sp % G, j = sp / G;

            const float* xp = x + ((size_t)(b * (NA * CH) + a * CH) * GG + sp);
            float v[CH];
            #pragma unroll
            for (int c = 0; c < CH; ++c) v[c] = xp[(size_t)c * GG];

            float px = sigmoidf(v[0]);
            float py = sigmoidf(v[1]);
            float pw = v[2], ph = v[3];
            float pconf = sigmoidf(v[4]);
            float bx = px + (float)i;
            float by = py + (float)j;
            float bw = expf(pw) * c_aw[a];
            float bh = expf(ph) * c_ah[a];

            float cx = tg[t * 6 + 2] * (float)G;
            float cy = tg[t * 6 + 3] * (float)G;
            float gw = tg[t * 6 + 4] * (float)G;
            float gh = tg[t * 6 + 5] * (float)G;
            int label = (int)tg[t * 6 + 1];
            float tx = cx - floorf(cx);
            float ty = cy - floorf(cy);
            float tw = logf(gw / c_aw[a] + 1e-16f);
            float th = logf(gh / c_ah[a] + 1e-16f);

            float b1x1 = bx - bw * 0.5f, b1x2 = bx + bw * 0.5f;
            float b1y1 = by - bh * 0.5f, b1y2 = by + bh * 0.5f;
            float b2x1 = cx - gw * 0.5f, b2x2 = cx + gw * 0.5f;
            float b2y1 = cy - gh * 0.5f, b2y2 = cy + gh * 0.5f;
            float iw = fmaxf(fminf(b1x2, b2x2) - fmaxf(b1x1, b2x1) + 1.0f, 0.0f);
            float ih = fmaxf(fminf(b1y2, b2y2) - fmaxf(b1y1, b2y1) + 1.0f, 0.0f);
            float inter = iw * ih;
            float a1 = (b1x2 - b1x1 + 1.0f) * (b1y2 - b1y1 + 1.0f);
            float a2 = (b2x2 - b2x1 + 1.0f) * (b2y2 - b2y1 + 1.0f);
            float iou = inter / (a1 + a2 - inter + 1e-16f);

            p[0] = (px - tx) * (px - tx);
            p[1] = (py - ty) * (py - ty);
            p[2] = (pw - tw) * (pw - tw);
            p[3] = (ph - th) * (ph - th);
            p[4] = (pconf - iou) * (pconf - iou);
            float cls = 0.0f;
            #pragma unroll
            for (int c = 0; c < NC; ++c) {
                float pc = fminf(fmaxf(sigmoidf(v[5 + c]), 1e-12f), 1.0f - 1e-12f);
                float tc = (c == label) ? 1.0f : 0.0f;
                cls -= tc * logf(pc) + (1.0f - tc) * logf(1.0f - pc);
            }
            p[6] = cls;
            p[7] = 1.0f;                             // n_obj
            p[5] = -pconf * pconf;                   // undo default noobj sum
            p[8] = -1.0f;                            // undo default noobj count
        }
    } else {
        int si = gid - NT;
        if (si < counts[1]) {                        // suppressed (non-obj) cell
            int cell = supp_list[si];
            int b = cell / (NA * GG);
            int a = (cell / GG) % NA;
            int sp = cell % GG;
            float pconf = sigmoidf(x[((size_t)(b * (NA * CH) + a * CH + 4)) * GG + sp]);
            p[5] = -pconf * pconf;
            p[8] = -1.0f;
        }
    }

    #pragma unroll
    for (int o = 32; o > 0; o >>= 1) {
        #pragma unroll
        for (int q = 0; q < 9; ++q) p[q] += __shfl_down(p[q], o);
    }
    int lane = threadIdx.x & 63;
    int wid  = threadIdx.x >> 6;
    if (lane == 0) {
        #pragma unroll
        for (int q = 0; q < 9; ++q) red[wid][q] = p[q];
    }
    __syncthreads();
    if (threadIdx.x < 9) {
        float sum = red[0][threadIdx.x] + red[1][threadIdx.x]
                  + red[2][threadIdx.x] + red[3][threadIdx.x];
        if (sum != 0.0f) atomicAdd(&acc[threadIdx.x], sum);
    }
}

// -------- Pass 4: finalize scalar loss --------
__global__ void k_final(const float* __restrict__ acc, float* __restrict__ loss_out) {
    float n_obj   = acc[7];
    float n_noobj = (float)CELLS + acc[8];
    float l = COORD_SCALE * (acc[0] + acc[1] + acc[2] + acc[3]) / n_obj
            + OBJ_SCALE * acc[4] / n_obj
            + NOOBJ_SCALE * acc[5] / n_noobj
            + CLS_SCALE * acc[6] / (n_obj * (float)NC);
    *loss_out = l;
}

extern "C" void kernel_launch(void* const* d_in, const int* in_sizes, int n_in,
                              void* d_out, int out_size, void* d_ws, size_t ws_size,
                              hipStream_t stream) {
    const float* x  = (const float*)d_in[0];
    const float* tg = (const float*)d_in[1];
    float* out = (float*)d_out;

    char* ws = (char*)d_ws;
    float* acc      = (float*)ws;                    // 16 floats
    int*   counts   = (int*)(ws + 64);               // 2 ints
    int2*  obj_list = (int2*)(ws + 128);             // 1024 * int2
    int*   supp_list= (int*)(ws + 128 + NT * 8);     // 5120 ints

    k_prep<<<1, NT, 0, stream>>>(tg, acc, counts, obj_list, supp_list);
    k_main<<<CELLS / 256, 256, 0, stream>>>(x, out, acc);
    k_corr<<<(NT + NT * NA + 255) / 256, 256, 0, stream>>>(x, tg, counts, obj_list, supp_list, acc);
    k_final<<<1, 1, 0, stream>>>(acc, out + (size_t)CELLS * CH);
}

// Round 3
// 69.334 us; speedup vs baseline: 1.6451x; 1.6451x over previous
//
#include <hip/hip_runtime.h>
#include <math.h>

#define G      26
#define NA     5
#define NC     20
#define NB     128
#define NT     1024
#define GG     (G*G)            // 676
#define CELLS  (NB*NA*GG)       // 432640
#define CH     (NC+5)           // 25
#define IGNORE_THRESH 0.6f
#define OBJ_SCALE   5.0f
#define NOOBJ_SCALE 1.0f
#define CLS_SCALE   1.0f
#define COORD_SCALE 1.0f
#define STRIDE_F    32.0f

__device__ __constant__ float c_aw[NA] = {1.08f, 3.42f, 6.63f, 9.42f, 16.62f};
__device__ __constant__ float c_ah[NA] = {1.19f, 4.41f, 11.38f, 5.11f, 10.52f};

__device__ __forceinline__ float sigmoidf(float v) {
    return 1.0f / (1.0f + expf(-v));
}

// -------- Pass 1: parallel target resolution (1 wave per target) --------
// 256 blocks x 256 threads. Each block redundantly packs all NT targets into
// LDS (cheap, L2-hot), then its 4 waves each resolve one target via a
// 16-entry-per-lane scan + single OR shuffle-reduce. Deterministic output
// slots (sentinel -1) -> no atomics, no counts, no memset dispatches.
__launch_bounds__(256)
__global__ void k_resolve(const float* __restrict__ tg,
                          float* __restrict__ acc,
                          int2* __restrict__ obj_list,
                          int* __restrict__ supp_list) {
    __shared__ int packed[NT];
    int tid = threadIdx.x;
    if (blockIdx.x == 0 && tid < 16) acc[tid] = 0.0f;

    #pragma unroll
    for (int q = 0; q < 4; ++q) {
        int t = tid + q * 256;
        int   b  = (int)tg[t * 6 + 0];
        float cx = tg[t * 6 + 2] * (float)G;
        float cy = tg[t * 6 + 3] * (float)G;
        float gw = tg[t * 6 + 4] * (float)G;
        float gh = tg[t * 6 + 5] * (float)G;
        int gi = (int)floorf(cx);
        int gj = (int)floorf(cy);
        float best = -1.0f;
        int bn = 0, bits = 0;
        #pragma unroll
        for (int a = 0; a < NA; ++a) {
            float inter = fminf(c_aw[a], gw) * fminf(c_ah[a], gh);
            float uni   = c_aw[a] * c_ah[a] + 1e-16f + gw * gh - inter;
            float iou   = inter / uni;
            if (iou > best) { best = iou; bn = a; }      // first max wins (jnp.argmax)
            if (iou > IGNORE_THRESH) bits |= (1 << a);
        }
        int key = (b * G + gj) * G + gi;                 // < 86528, fits 17 bits
        packed[t] = (key << 8) | (bn << 5) | bits;
    }
    __syncthreads();

    int t    = blockIdx.x * 4 + (tid >> 6);              // wave -> target
    int lane = tid & 63;
    int me    = packed[t];
    int mykey = me >> 8;
    int mybn  = (me >> 5) & 7;
    int mybits = me & 31;

    // agg: bits0-4 used anchors, bits5-9 earlier supp bits, bit10 not-winner
    int agg = 0;
    #pragma unroll
    for (int s = 0; s < 16; ++s) {
        int o  = lane + s * 64;
        int pv = packed[o];
        if ((pv >> 8) == mykey) {
            int obn = (pv >> 5) & 7;
            agg |= (1 << obn);                           // used
            if (o > t && obn == mybn) agg |= (1 << 10);  // later target owns cell
            if (o < t) agg |= (pv & 31) << 5;            // earlier supp rep
        }
    }
    #pragma unroll
    for (int off = 32; off > 0; off >>= 1) agg |= __shfl_xor(agg, off);

    if (lane == 0) {
        int used    = agg & 31;
        int earlier = (agg >> 5) & 31;
        bool winner = !(agg & (1 << 10));
        int cell0 = (mykey / GG) * (NA * GG) + (mykey % GG);
        obj_list[t] = winner ? make_int2(cell0 + mybn * GG, t) : make_int2(-1, -1);
        #pragma unroll
        for (int a = 0; a < NA; ++a) {
            bool s = (mybits >> a & 1) && !(earlier >> a & 1) && !(used >> a & 1);
            supp_list[t * NA + a] = s ? (cell0 + a * GG) : -1;
        }
    }
}

// -------- Pass 2: pure streaming elementwise + default noobj sum --------
// 2 cells/thread, float2 loads (pairs never straddle panel/row: GG and G even).
__launch_bounds__(256)
__global__ void k_main(const float* __restrict__ x,
                       float* __restrict__ out,
                       float* __restrict__ acc) {
    __shared__ float stage[512 * CH];   // 51200 B
    __shared__ float red[4];

    int tid = threadIdx.x;
    int cell0 = blockIdx.x * 512 + tid * 2;
    int sp = cell0 % GG;                 // even
    int pa = cell0 / GG;                 // b*NA + a
    int a  = pa % NA;
    int i0 = sp % G, j0 = sp / G;        // i0 even <= 24 -> pair shares row

    const float2* xp = (const float2*)(x + (size_t)pa * (CH * GG) + sp);
    float2 v[CH];
    #pragma unroll
    for (int c = 0; c < CH; ++c) v[c] = xp[c * (GG / 2)];

    float px0 = sigmoidf(v[0].x), px1 = sigmoidf(v[0].y);
    float py0 = sigmoidf(v[1].x), py1 = sigmoidf(v[1].y);
    float pc0 = sigmoidf(v[4].x), pc1 = sigmoidf(v[4].y);
    float aw = c_aw[a], ah = c_ah[a];

    float* s = &stage[tid * 2 * CH];
    s[0] = (px0 + (float)i0) * STRIDE_F;
    s[1] = (py0 + (float)j0) * STRIDE_F;
    s[2] = expf(v[2].x) * aw * STRIDE_F;
    s[3] = expf(v[3].x) * ah * STRIDE_F;
    s[4] = pc0;
    s[CH + 0] = (px1 + (float)(i0 + 1)) * STRIDE_F;
    s[CH + 1] = (py1 + (float)j0) * STRIDE_F;
    s[CH + 2] = expf(v[2].y) * aw * STRIDE_F;
    s[CH + 3] = expf(v[3].y) * ah * STRIDE_F;
    s[CH + 4] = pc1;
    #pragma unroll
    for (int c = 0; c < NC; ++c) {
        s[5 + c]      = sigmoidf(v[5 + c].x);
        s[CH + 5 + c] = sigmoidf(v[5 + c].y);
    }

    // default noobj contribution (count handled in finalize)
    float p = pc0 * pc0 + pc1 * pc1;
    #pragma unroll
    for (int o = 32; o > 0; o >>= 1) p += __shfl_down(p, o);
    if ((tid & 63) == 0) red[tid >> 6] = p;
    __syncthreads();
    if (tid == 0) atomicAdd(&acc[5], red[0] + red[1] + red[2] + red[3]);

    // coalesced copy-out: block covers 512*25 contiguous floats
    float2* ob = (float2*)(out + (size_t)blockIdx.x * (512 * CH));
    const float2* st = (const float2*)stage;
    #pragma unroll
    for (int k = 0; k < CH; ++k)
        ob[k * 256 + tid] = st[k * 256 + tid];
}

// -------- Pass 3: sparse corrections + finalize (single block) --------
__launch_bounds__(1024)
__global__ void k_corr_final(const float* __restrict__ x,
                             const float* __restrict__ tg,
                             const int2* __restrict__ obj_list,
                             const int* __restrict__ supp_list,
                             const float* __restrict__ acc,
                             float* __restrict__ loss_out) {
    __shared__ float red[16][9];
    int t = threadIdx.x;

    float p[9];
    #pragma unroll
    for (int q = 0; q < 9; ++q) p[q] = 0.0f;

    int2 it = obj_list[t];
    if (it.x >= 0) {
        int cell = it.x, tt = it.y;
        int pa = cell / GG;
        int a  = pa % NA;
        int sp = cell % GG;
        int i = sp % G, j = sp / G;

        const float* xp = x + (size_t)pa * (CH * GG) + sp;
        float v[CH];
        #pragma unroll
        for (int c = 0; c < CH; ++c) v[c] = xp[(size_t)c * GG];

        float px = sigmoidf(v[0]);
        float py = sigmoidf(v[1]);
        float pw = v[2], ph = v[3];
        float pconf = sigmoidf(v[4]);
        float bx = px + (float)i;
        float by = py + (float)j;
        float bw = expf(pw) * c_aw[a];
        float bh = expf(ph) * c_ah[a];

        float cx = tg[tt * 6 + 2] * (float)G;
        float cy = tg[tt * 6 + 3] * (float)G;
        float gw = tg[tt * 6 + 4] * (float)G;
        float gh = tg[tt * 6 + 5] * (float)G;
        int label = (int)tg[tt * 6 + 1];
        float tx = cx - floorf(cx);
        float ty = cy - floorf(cy);
        float tw = logf(gw / c_aw[a] + 1e-16f);
        float th = logf(gh / c_ah[a] + 1e-16f);

        float b1x1 = bx - bw * 0.5f, b1x2 = bx + bw * 0.5f;
        float b1y1 = by - bh * 0.5f, b1y2 = by + bh * 0.5f;
        float b2x1 = cx - gw * 0.5f, b2x2 = cx + gw * 0.5f;
        float b2y1 = cy - gh * 0.5f, b2y2 = cy + gh * 0.5f;
        float iw = fmaxf(fminf(b1x2, b2x2) - fmaxf(b1x1, b2x1) + 1.0f, 0.0f);
        float ih = fmaxf(fminf(b1y2, b2y2) - fmaxf(b1y1, b2y1) + 1.0f, 0.0f);
        float inter = iw * ih;
        float a1 = (b1x2 - b1x1 + 1.0f) * (b1y2 - b1y1 + 1.0f);
        float a2 = (b2x2 - b2x1 + 1.0f) * (b2y2 - b2y1 + 1.0f);
        float iou = inter / (a1 + a2 - inter + 1e-16f);

        p[0] = (px - tx) * (px - tx);
        p[1] = (py - ty) * (py - ty);
        p[2] = (pw - tw) * (pw - tw);
        p[3] = (ph - th) * (ph - th);
        p[4] = (pconf - iou) * (pconf - iou);
        float cls = 0.0f;
        #pragma unroll
        for (int c = 0; c < NC; ++c) {
            float pc = fminf(fmaxf(sigmoidf(v[5 + c]), 1e-12f), 1.0f - 1e-12f);
            float tc = (c == label) ? 1.0f : 0.0f;
            cls -= tc * logf(pc) + (1.0f - tc) * logf(1.0f - pc);
        }
        p[6] = cls;
        p[7] = 1.0f;                       // n_obj
        p[5] = -pconf * pconf;             // undo default noobj sum
        p[8] = -1.0f;                      // undo default noobj count
    }

    #pragma unroll
    for (int q = 0; q < NA; ++q) {
        int cell = supp_list[t * NA + q];
        if (cell >= 0) {
            int pa = cell / GG;
            int sp = cell % GG;
            float pconf = sigmoidf(x[(size_t)(pa * CH + 4) * GG + sp]);
            p[5] -= pconf * pconf;
            p[8] -= 1.0f;
        }
    }

    #pragma unroll
    for (int o = 32; o > 0; o >>= 1) {
        #pragma unroll
        for (int q = 0; q < 9; ++q) p[q] += __shfl_down(p[q], o);
    }
    int lane = t & 63, wid = t >> 6;
    if (lane == 0) {
        #pragma unroll
        for (int q = 0; q < 9; ++q) red[wid][q] = p[q];
    }
    __syncthreads();

    if (t == 0) {
        float s[9];
        #pragma unroll
        for (int q = 0; q < 9; ++q) {
            float acc_q = 0.0f;
            for (int w = 0; w < 16; ++w) acc_q += red[w][q];
            s[q] = acc_q;
        }
        float n_obj   = s[7];
        float n_noobj = (float)CELLS + s[8];
        float noobj_sum = acc[5] + s[5];
        float l = COORD_SCALE * (s[0] + s[1] + s[2] + s[3]) / n_obj
                + OBJ_SCALE * s[4] / n_obj
                + NOOBJ_SCALE * noobj_sum / n_noobj
                + CLS_SCALE * s[6] / (n_obj * (float)NC);
        *loss_out = l;
    }
}

extern "C" void kernel_launch(void* const* d_in, const int* in_sizes, int n_in,
                              void* d_out, int out_size, void* d_ws, size_t ws_size,
                              hipStream_t stream) {
    const float* x  = (const float*)d_in[0];
    const float* tg = (const float*)d_in[1];
    float* out = (float*)d_out;

    char* ws = (char*)d_ws;
    float* acc       = (float*)ws;                   // 16 floats
    int2*  obj_list  = (int2*)(ws + 64);             // 1024 * int2 (all slots written)
    int*   supp_list = (int*)(ws + 64 + NT * 8);     // 5120 ints  (all slots written)

    k_resolve<<<NT / 4, 256, 0, stream>>>(tg, acc, obj_list, supp_list);
    k_main<<<CELLS / 512, 256, 0, stream>>>(x, out, acc);
    k_corr_final<<<1, NT, 0, stream>>>(x, tg, obj_list, supp_list, acc,
                                       out + (size_t)CELLS * CH);
}